// Round 10
// baseline (233.660 us; speedup 1.0000x reference)
//
#include <hip/hip_runtime.h>
#include <hip/hip_fp16.h>

typedef int v4i  __attribute__((ext_vector_type(4)));
typedef const unsigned __attribute__((address_space(1)))* gas_t;
typedef unsigned __attribute__((address_space(3)))* las_t;

#define DIVFACTOR (1.0f / 16129.0f)

__device__ __forceinline__ unsigned pack4v(v4i v) {
    return (unsigned)(v[0] & 0xFF) | ((unsigned)(v[1] & 0xFF) << 8) |
           ((unsigned)(v[2] & 0xFF) << 16) | ((unsigned)v[3] << 24);
}
__device__ __forceinline__ unsigned pack4(int4 v) {
    return (unsigned)(v.x & 0xFF) | ((unsigned)(v.y & 0xFF) << 8) |
           ((unsigned)(v.z & 0xFF) << 16) | ((unsigned)v.w << 24);
}

__device__ __forceinline__ void gload16(const void* g, void* l) {
    __builtin_amdgcn_global_load_lds((gas_t)g, (las_t)l, 16, 0, 0);
}

// ---------------- pass 1: repack int32 -> half-tile-linear swizzled int8 ----------------
// Per matrix (16 MB, uint4 units): idx = (((p*32 + kt)*2 + h) << 10) + row*8 + (s ^ (row&7))
// NT loads: x/w are single-use — don't let 134 MB of int32 flush the L3 (packed output
// and GEMM panels stay resident).
__global__ __launch_bounds__(256) void pack_kernel(
    const int* __restrict__ x, const int* __restrict__ w, uint4* __restrict__ ws)
{
    const int u   = blockIdx.x * 256 + threadIdx.x;   // 0..2^20-1
    const int s   = u & 7;
    const int row = (u >> 3) & 127;
    const int h   = (u >> 10) & 1;
    const int kt  = (u >> 11) & 31;
    const int p   = u >> 16;
    const int* src = (blockIdx.y == 0) ? x : w;
    uint4* dst = ws + (size_t)blockIdx.y * 1048576;

    const int grow = p * 256 + h * 128 + row;
    const v4i* sp = (const v4i*)(src + (size_t)grow * 4096 + kt * 128 + s * 16);
    v4i s0 = __builtin_nontemporal_load(sp + 0);
    v4i s1 = __builtin_nontemporal_load(sp + 1);
    v4i s2 = __builtin_nontemporal_load(sp + 2);
    v4i s3 = __builtin_nontemporal_load(sp + 3);
    uint4 d = make_uint4(pack4v(s0), pack4v(s1), pack4v(s2), pack4v(s3));
    dst[(((size_t)((p * 32 + kt) * 2 + h)) << 10) + row * 8 + (s ^ (row & 7))] = d;
}

// ---------------- pass 2: 256x256 8-phase i8 GEMM, 16x16x64 MFMA, A read-ahead ----------------
// BK=128, 8 waves (2Mx4N). Phase k issues the A-frag ds_reads for phase k+1's cluster
// (afrP/afrN static double-buffer); B-frags burst post-VM (bR0 @ ph5, bR1 @ ph3).
// Stage map: ph0: b1B0+b1A1(KB+1)  ph1: b1B1(KB+1)  ph2: b0B0(KB+2)  ph3: b0B1(KB+2)
//            ph4: b0A0(KB+2)  ph5: b0A1(KB+2)  ph6: -  ph7: b1A0(KB+3)
// vmcnt: VM4@ph3 (b1 complete), VM4@ph5 (b0B complete), VM2@ph7 (b0A complete).
// Every read is post-covering-VM+BAR; every stage >=1 barrier after its region's last read.
__global__ __launch_bounds__(512, 1) void i8gemm_8ph(
    const uint4* __restrict__ Ap, const uint4* __restrict__ Bp,
    const float* __restrict__ scale_x, const float* __restrict__ scale_w,
    const void* __restrict__ bias, float* __restrict__ out)
{
    __shared__ uint4 ldsq[8192];          // 128 KiB
    char* ldsb = (char*)ldsq;

    // T1: XCD-chunked swizzle (256 wgs, 8 XCDs, 32 contiguous tiles each)
    const int bid = blockIdx.x;
    const int swb = ((bid & 7) << 5) | (bid >> 3);
    const int bx  = swb & 15;             // N tile
    const int by  = swb >> 4;             // M tile

    const int t    = threadIdx.x;
    const int lane = t & 63;
    const int wid  = t >> 6;
    const int wr   = wid >> 2;            // 0..1 -> 128 out rows
    const int wc   = wid & 3;             // 0..3 -> 64 out cols
    const int r    = lane & 15;
    const int g    = lane >> 4;

    const uint4* aBase = Ap + (size_t)by * 65536 + t;
    const uint4* bBase = Bp + (size_t)bx * 65536 + t;

    const int sl0 = ((g ^ (r & 7)) << 4);
    const int sl1 = (((4 + g) ^ (r & 7)) << 4);
    const int aoff0 = wr * 16384 + r * 128 + sl0;                       // + m*2048
    const int aoff1 = wr * 16384 + r * 128 + sl1;
    const int boff0 = 32768 + (wc >> 1) * 16384 + ((wc & 1) * 64 + r) * 128 + sl0;  // + n*2048
    const int boff1 = 32768 + (wc >> 1) * 16384 + ((wc & 1) * 64 + r) * 128 + sl1;

#define ARD(BUF,M,KS) (*(const v4i*)(ldsb + (BUF)*65536 + aoff##KS + (M)*2048))
#define BRD(BUF,N,KS) (*(const v4i*)(ldsb + (BUF)*65536 + boff##KS + (N)*2048))

#define STAGE(KT, MAT, HALF, BUF) do{ \
    const uint4* s_ = ((MAT) ? bBase : aBase) + (KT)*2048 + (HALF)*1024; \
    char* d_ = ldsb + (BUF)*65536 + (MAT)*32768 + (HALF)*16384 + t*16; \
    gload16((const void*)s_, (void*)d_); \
    gload16((const void*)(s_ + 512), (void*)(d_ + 8192)); \
}while(0)

#define BAR asm volatile("s_barrier" ::: "memory")
#define VM4 asm volatile("s_waitcnt vmcnt(4)" ::: "memory")
#define VM2 asm volatile("s_waitcnt vmcnt(2)" ::: "memory")
#define VM0 asm volatile("s_waitcnt vmcnt(0)" ::: "memory")

// read A m-pair {M0,M0+1} of BUF into DST (4 x ds_read_b128)
#define RD_A2TO(BUF,M0,DST) do{ \
    DST[0][0] = ARD(BUF,M0,0);     DST[0][1] = ARD(BUF,M0,1); \
    DST[1][0] = ARD(BUF,(M0)+1,0); DST[1][1] = ARD(BUF,(M0)+1,1); \
}while(0)

#define RD_B8(BUF,ARR) do{ \
    _Pragma("unroll") for (int n_ = 0; n_ < 4; ++n_) { \
        ARR[n_][0] = BRD(BUF,n_,0); ARR[n_][1] = BRD(BUF,n_,1); } \
}while(0)

// 16 MFMA: acc rows M0,M0+1 x 4 n x 2 ks, A from AFR (2x2), B from BARR (4x2)
#define CLUSTER(BARR,AFR,M0) do{ \
    __builtin_amdgcn_s_setprio(1); \
    _Pragma("unroll") for (int n_ = 0; n_ < 4; ++n_) { \
        acc[M0][n_]     = __builtin_amdgcn_mfma_i32_16x16x64_i8(AFR[0][0], BARR[n_][0], acc[M0][n_], 0,0,0); \
        acc[M0][n_]     = __builtin_amdgcn_mfma_i32_16x16x64_i8(AFR[0][1], BARR[n_][1], acc[M0][n_], 0,0,0); \
        acc[(M0)+1][n_] = __builtin_amdgcn_mfma_i32_16x16x64_i8(AFR[1][0], BARR[n_][0], acc[(M0)+1][n_], 0,0,0); \
        acc[(M0)+1][n_] = __builtin_amdgcn_mfma_i32_16x16x64_i8(AFR[1][1], BARR[n_][1], acc[(M0)+1][n_], 0,0,0); } \
    __builtin_amdgcn_s_setprio(0); \
}while(0)

#define ITER(KB, STEADY) do{ \
    RD_A2TO(0,2,afrN); STAGE((KB)+1,1,0,1); STAGE((KB)+1,0,1,1); BAR; CLUSTER(bR0,afrP,0); BAR;  /* ph0 */ \
    RD_A2TO(0,4,afrP); STAGE((KB)+1,1,1,1); BAR; CLUSTER(bR0,afrN,2); BAR;                        /* ph1 */ \
    RD_A2TO(0,6,afrN); if (STEADY) STAGE((KB)+2,1,0,0); BAR; CLUSTER(bR0,afrP,4); BAR;            /* ph2 */ \
    if (STEADY) { STAGE((KB)+2,1,1,0); VM4; } else { VM0; } \
    BAR; RD_B8(1,bR1); RD_A2TO(1,0,afrP); CLUSTER(bR0,afrN,6); BAR;                               /* ph3 */ \
    RD_A2TO(1,2,afrN); if (STEADY) STAGE((KB)+2,0,0,0); BAR; CLUSTER(bR1,afrP,0); BAR;            /* ph4 */ \
    RD_A2TO(1,4,afrP); if (STEADY) { STAGE((KB)+2,0,1,0); VM4; } \
    BAR; if (STEADY) RD_B8(0,bR0); CLUSTER(bR1,afrN,2); BAR;                                      /* ph5 */ \
    RD_A2TO(1,6,afrN); BAR; CLUSTER(bR1,afrP,4); BAR;                                             /* ph6 */ \
    if (STEADY) { STAGE((KB)+3,0,0,1); VM2; } \
    BAR; if (STEADY) RD_A2TO(0,0,afrP); CLUSTER(bR1,afrN,6); BAR;                                 /* ph7 */ \
}while(0)

    v4i acc[8][4];
    #pragma unroll
    for (int m = 0; m < 8; ++m)
        #pragma unroll
        for (int n = 0; n < 4; ++n) acc[m][n] = (v4i){0, 0, 0, 0};
    v4i afrP[2][2], afrN[2][2], bR0[4][2], bR1[4][2];

    // prologue: buf0 <- kt0 (B0,B1,A0,A1); buf1.A0 <- kt1; VM2 leaves only b1A0 in flight.
    STAGE(0,1,0,0); STAGE(0,1,1,0); STAGE(0,0,0,0); STAGE(0,0,1,0);
    STAGE(1,0,0,1);
    VM2; BAR;
    RD_B8(0,bR0); RD_A2TO(0,0,afrP);

    for (int i = 0; i < 15; ++i) { ITER(2 * i, 1); }
    ITER(30, 0);

#undef ITER
#undef CLUSTER
#undef RD_B8
#undef RD_A2TO
#undef VM0
#undef VM2
#undef VM4
#undef BAR
#undef STAGE
#undef BRD
#undef ARD

    // ---- epilogue (verified 16x16 C/D mapping) ----
    const float p0  = ((const float*)bias)[0];
    const float ap0 = fabsf(p0);
    const bool bias_is_f32 = (ap0 >= 1e-6f && ap0 <= 1.0f);

    float swv[4], bvv[4];
    #pragma unroll
    for (int n = 0; n < 4; ++n) {
        int col = bx * 256 + wc * 64 + n * 16 + r;
        swv[n] = scale_w[col];
        bvv[n] = bias_is_f32 ? ((const float*)bias)[col]
                             : __half2float(((const __half*)bias)[col]);
    }

    #pragma unroll
    for (int m = 0; m < 8; ++m) {
        float sxr[4];
        #pragma unroll
        for (int q = 0; q < 4; ++q)
            sxr[q] = scale_x[by * 256 + wr * 128 + m * 16 + g * 4 + q] * DIVFACTOR;
        #pragma unroll
        for (int q = 0; q < 4; ++q) {
            int row = by * 256 + wr * 128 + m * 16 + g * 4 + q;
            #pragma unroll
            for (int n = 0; n < 4; ++n) {
                int col = bx * 256 + wc * 64 + n * 16 + r;
                float v = (float)acc[m][n][q] * sxr[q] * swv[n] + bvv[n];
                out[(size_t)row * 4096 + col] = __half2float(__float2half(v));
            }
        }
    }
}

// ---------------- fallback (round-1 fused kernel, used only if ws too small) ----------------
__global__ __launch_bounds__(256) void i8gemm_kernel(
    const int* __restrict__ x, const int* __restrict__ w,
    const float* __restrict__ scale_x, const float* __restrict__ scale_w,
    const void* __restrict__ bias, float* __restrict__ out)
{
    __shared__ int lds[4096];
    const int t = threadIdx.x, bx = blockIdx.x, by = blockIdx.y;
    const int lane = t & 63, wid = t >> 6, wr = wid >> 1, wc = wid & 1;
    const int th = t >> 4, tl = t & 15;
    const int* aptr = x + (size_t)(by * 128 + th) * 4096 + tl * 4;
    const int* bptr = w + (size_t)(bx * 128 + th) * 4096 + tl * 4;
    const int wbase = th * 16 + (tl ^ (((th >> 1) & 3) << 2));
    const int r = lane & 15, g = lane >> 4;
    const int sw4 = (r >> 1) & 3;
    const int a_rd = (wr * 64 + r) * 16 + ((g ^ sw4) << 2);
    const int b_rd = 2048 + (wc * 64 + r) * 16 + ((g ^ sw4) << 2);

    v4i acc[4][4];
    #pragma unroll
    for (int m = 0; m < 4; ++m)
        #pragma unroll
        for (int n = 0; n < 4; ++n) acc[m][n] = (v4i){0, 0, 0, 0};

    int4 va[8], vb[8];
    #pragma unroll
    for (int j = 0; j < 8; ++j) { va[j] = *(const int4*)(aptr + j * 65536); vb[j] = *(const int4*)(bptr + j * 65536); }

    for (int kt = 0; kt < 64; ++kt) {
        __syncthreads();
        #pragma unroll
        for (int j = 0; j < 8; ++j) {
            lds[wbase + j * 256]        = (int)pack4(va[j]);
            lds[2048 + wbase + j * 256] = (int)pack4(vb[j]);
        }
        __syncthreads();
        if (kt < 63) {
            const int* ap = aptr + (kt + 1) * 64;
            const int* bp = bptr + (kt + 1) * 64;
            #pragma unroll
            for (int j = 0; j < 8; ++j) { va[j] = *(const int4*)(ap + j * 65536); vb[j] = *(const int4*)(bp + j * 65536); }
        }
        v4i af[4], bf[4];
        #pragma unroll
        for (int m = 0; m < 4; ++m) af[m] = *(const v4i*)&lds[a_rd + m * 256];
        #pragma unroll
        for (int n = 0; n < 4; ++n) bf[n] = *(const v4i*)&lds[b_rd + n * 256];
        #pragma unroll
        for (int m = 0; m < 4; ++m)
            #pragma unroll
            for (int n = 0; n < 4; ++n)
                acc[m][n] = __builtin_amdgcn_mfma_i32_16x16x64_i8(af[m], bf[n], acc[m][n], 0, 0, 0);
    }

    const float p0 = ((const float*)bias)[0];
    const float ap0 = fabsf(p0);
    const bool bias_is_f32 = (ap0 >= 1e-6f && ap0 <= 1.0f);
    float sxv[4][4];
    #pragma unroll
    for (int m = 0; m < 4; ++m)
        #pragma unroll
        for (int q = 0; q < 4; ++q)
            sxv[m][q] = scale_x[by * 128 + wr * 64 + m * 16 + g * 4 + q] * DIVFACTOR;
    float swv[4], bvv[4];
    #pragma unroll
    for (int n = 0; n < 4; ++n) {
        int col = bx * 128 + wc * 64 + n * 16 + r;
        swv[n] = scale_w[col];
        bvv[n] = bias_is_f32 ? ((const float*)bias)[col] : __half2float(((const __half*)bias)[col]);
    }
    #pragma unroll
    for (int m = 0; m < 4; ++m)
        #pragma unroll
        for (int q = 0; q < 4; ++q) {
            int row = by * 128 + wr * 64 + m * 16 + g * 4 + q;
            float s = sxv[m][q];
            #pragma unroll
            for (int n = 0; n < 4; ++n) {
                int col = bx * 128 + wc * 64 + n * 16 + r;
                float v = (float)acc[m][n][q] * s * swv[n] + bvv[n];
                out[(size_t)row * 4096 + col] = __half2float(__float2half(v));
            }
        }
}

extern "C" void kernel_launch(void* const* d_in, const int* in_sizes, int n_in,
                              void* d_out, int out_size, void* d_ws, size_t ws_size,
                              hipStream_t stream) {
    const int*   x   = (const int*)d_in[0];
    const float* sx  = (const float*)d_in[1];
    const int*   w   = (const int*)d_in[2];
    const float* sw  = (const float*)d_in[3];
    const void*  bi  = d_in[4];
    float*       out = (float*)d_out;
    (void)in_sizes; (void)n_in; (void)out_size;

    if (ws_size >= (size_t)33554432) {
        uint4* ws = (uint4*)d_ws;
        hipLaunchKernelGGL(pack_kernel, dim3(4096, 2, 1), dim3(256, 1, 1), 0, stream, x, w, ws);
        hipLaunchKernelGGL(i8gemm_8ph, dim3(256, 1, 1), dim3(512, 1, 1), 0, stream,
                           ws, ws + 1048576, sx, sw, bi, out);
    } else {
        hipLaunchKernelGGL(i8gemm_kernel, dim3(32, 32, 1), dim3(256, 1, 1), 0, stream,
                           x, w, sx, sw, bi, out);
    }
}

// Round 11
// 230.854 us; speedup vs baseline: 1.0122x; 1.0122x over previous
//
#include <hip/hip_runtime.h>
#include <hip/hip_fp16.h>

typedef int v4i  __attribute__((ext_vector_type(4)));
typedef const unsigned __attribute__((address_space(1)))* gas_t;
typedef unsigned __attribute__((address_space(3)))* las_t;

#define DIVFACTOR (1.0f / 16129.0f)

__device__ __forceinline__ unsigned pack4(int4 v) {
    return (unsigned)(v.x & 0xFF) | ((unsigned)(v.y & 0xFF) << 8) |
           ((unsigned)(v.z & 0xFF) << 16) | ((unsigned)v.w << 24);
}

__device__ __forceinline__ void gload16(const void* g, void* l) {
    __builtin_amdgcn_global_load_lds((gas_t)g, (las_t)l, 16, 0, 0);
}

// ---------------- pass 1: repack int32 -> half-tile-linear swizzled int8 ----------------
// Per matrix (16 MB, uint4 units): idx = (((p*32 + kt)*2 + h) << 10) + row*8 + (s ^ (row&7))
// 2 rows/thread (row6, row6+64): 8 loads issued up-front -> 2x in-flight bytes per wave
// (pack was latency-marginal at 4 loads/thread: 8 KB/CU in flight vs 9.2 KB needed).
__global__ __launch_bounds__(256) void pack_kernel(
    const int* __restrict__ x, const int* __restrict__ w, uint4* __restrict__ ws)
{
    const int u    = blockIdx.x * 256 + threadIdx.x;   // 0..2^19-1
    const int s    = u & 7;
    const int row6 = (u >> 3) & 63;
    const int h    = (u >> 9) & 1;
    const int kt   = (u >> 10) & 31;
    const int p    = u >> 15;
    const int* src = (blockIdx.y == 0) ? x : w;
    uint4* dst = ws + (size_t)blockIdx.y * 1048576;

    const int grow0 = p * 256 + h * 128 + row6;        // rows row6 and row6+64
    const int4* sp0 = (const int4*)(src + (size_t)grow0 * 4096 + kt * 128 + s * 16);
    const int4* sp1 = (const int4*)((const int*)sp0 + (size_t)64 * 4096);
    int4 a0 = sp0[0], a1 = sp0[1], a2 = sp0[2], a3 = sp0[3];
    int4 b0 = sp1[0], b1 = sp1[1], b2 = sp1[2], b3 = sp1[3];
    uint4 d0 = make_uint4(pack4(a0), pack4(a1), pack4(a2), pack4(a3));
    uint4 d1 = make_uint4(pack4(b0), pack4(b1), pack4(b2), pack4(b3));
    const size_t base = (((size_t)((p * 32 + kt) * 2 + h)) << 10) + row6 * 8 + (s ^ (row6 & 7));
    dst[base]       = d0;
    dst[base + 512] = d1;    // (row6+64)*8, same swizzle since (row6+64)&7 == row6&7
}

// ---------------- pass 2: 256x256 8-phase i8 GEMM, 16x16x64 MFMA, A read-ahead ----------------
// BK=128, 8 waves (2Mx4N). Phase k issues the A-frag ds_reads for phase k+1's cluster
// (afrP/afrN static double-buffer); B-frags burst post-VM (bR0 @ ph5, bR1 @ ph3).
// Stage map: ph0: b1B0+b1A1(KB+1)  ph1: b1B1(KB+1)  ph2: b0B0(KB+2)  ph3: b0B1(KB+2)
//            ph4: b0A0(KB+2)  ph5: b0A1(KB+2)  ph6: -  ph7: b1A0(KB+3)
// vmcnt: VM4@ph3 (b1 complete), VM4@ph5 (b0B complete), VM2@ph7 (b0A complete).
// CLUSTER is ks-outer: 8 independent acc chains between dependent reuses (dep distance 8).
__global__ __launch_bounds__(512, 1) void i8gemm_8ph(
    const uint4* __restrict__ Ap, const uint4* __restrict__ Bp,
    const float* __restrict__ scale_x, const float* __restrict__ scale_w,
    const void* __restrict__ bias, float* __restrict__ out)
{
    __shared__ uint4 ldsq[8192];          // 128 KiB
    char* ldsb = (char*)ldsq;

    // T1: XCD-chunked swizzle (256 wgs, 8 XCDs, 32 contiguous tiles each)
    const int bid = blockIdx.x;
    const int swb = ((bid & 7) << 5) | (bid >> 3);
    const int bx  = swb & 15;             // N tile
    const int by  = swb >> 4;             // M tile

    const int t    = threadIdx.x;
    const int lane = t & 63;
    const int wid  = t >> 6;
    const int wr   = wid >> 2;            // 0..1 -> 128 out rows
    const int wc   = wid & 3;             // 0..3 -> 64 out cols
    const int r    = lane & 15;
    const int g    = lane >> 4;

    const uint4* aBase = Ap + (size_t)by * 65536 + t;
    const uint4* bBase = Bp + (size_t)bx * 65536 + t;

    const int sl0 = ((g ^ (r & 7)) << 4);
    const int sl1 = (((4 + g) ^ (r & 7)) << 4);
    const int aoff0 = wr * 16384 + r * 128 + sl0;                       // + m*2048
    const int aoff1 = wr * 16384 + r * 128 + sl1;
    const int boff0 = 32768 + (wc >> 1) * 16384 + ((wc & 1) * 64 + r) * 128 + sl0;  // + n*2048
    const int boff1 = 32768 + (wc >> 1) * 16384 + ((wc & 1) * 64 + r) * 128 + sl1;

#define ARD(BUF,M,KS) (*(const v4i*)(ldsb + (BUF)*65536 + aoff##KS + (M)*2048))
#define BRD(BUF,N,KS) (*(const v4i*)(ldsb + (BUF)*65536 + boff##KS + (N)*2048))

#define STAGE(KT, MAT, HALF, BUF) do{ \
    const uint4* s_ = ((MAT) ? bBase : aBase) + (KT)*2048 + (HALF)*1024; \
    char* d_ = ldsb + (BUF)*65536 + (MAT)*32768 + (HALF)*16384 + t*16; \
    gload16((const void*)s_, (void*)d_); \
    gload16((const void*)(s_ + 512), (void*)(d_ + 8192)); \
}while(0)

#define BAR asm volatile("s_barrier" ::: "memory")
#define VM4 asm volatile("s_waitcnt vmcnt(4)" ::: "memory")
#define VM2 asm volatile("s_waitcnt vmcnt(2)" ::: "memory")
#define VM0 asm volatile("s_waitcnt vmcnt(0)" ::: "memory")

// read A m-pair {M0,M0+1} of BUF into DST (4 x ds_read_b128)
#define RD_A2TO(BUF,M0,DST) do{ \
    DST[0][0] = ARD(BUF,M0,0);     DST[0][1] = ARD(BUF,M0,1); \
    DST[1][0] = ARD(BUF,(M0)+1,0); DST[1][1] = ARD(BUF,(M0)+1,1); \
}while(0)

#define RD_B8(BUF,ARR) do{ \
    _Pragma("unroll") for (int n_ = 0; n_ < 4; ++n_) { \
        ARR[n_][0] = BRD(BUF,n_,0); ARR[n_][1] = BRD(BUF,n_,1); } \
}while(0)

// 16 MFMA, ks-outer: 8 independent chains per ks step (dep distance 8)
#define CLUSTER(BARR,AFR,M0) do{ \
    __builtin_amdgcn_s_setprio(1); \
    _Pragma("unroll") for (int ks_ = 0; ks_ < 2; ++ks_) { \
        _Pragma("unroll") for (int n_ = 0; n_ < 4; ++n_) { \
            acc[M0][n_]     = __builtin_amdgcn_mfma_i32_16x16x64_i8(AFR[0][ks_], BARR[n_][ks_], acc[M0][n_], 0,0,0); \
            acc[(M0)+1][n_] = __builtin_amdgcn_mfma_i32_16x16x64_i8(AFR[1][ks_], BARR[n_][ks_], acc[(M0)+1][n_], 0,0,0); } } \
    __builtin_amdgcn_s_setprio(0); \
}while(0)

#define ITER(KB, STEADY) do{ \
    RD_A2TO(0,2,afrN); STAGE((KB)+1,1,0,1); STAGE((KB)+1,0,1,1); BAR; CLUSTER(bR0,afrP,0); BAR;  /* ph0 */ \
    RD_A2TO(0,4,afrP); STAGE((KB)+1,1,1,1); BAR; CLUSTER(bR0,afrN,2); BAR;                        /* ph1 */ \
    RD_A2TO(0,6,afrN); if (STEADY) STAGE((KB)+2,1,0,0); BAR; CLUSTER(bR0,afrP,4); BAR;            /* ph2 */ \
    if (STEADY) { STAGE((KB)+2,1,1,0); VM4; } else { VM0; } \
    BAR; RD_B8(1,bR1); RD_A2TO(1,0,afrP); CLUSTER(bR0,afrN,6); BAR;                               /* ph3 */ \
    RD_A2TO(1,2,afrN); if (STEADY) STAGE((KB)+2,0,0,0); BAR; CLUSTER(bR1,afrP,0); BAR;            /* ph4 */ \
    RD_A2TO(1,4,afrP); if (STEADY) { STAGE((KB)+2,0,1,0); VM4; } \
    BAR; if (STEADY) RD_B8(0,bR0); CLUSTER(bR1,afrN,2); BAR;                                      /* ph5 */ \
    RD_A2TO(1,6,afrN); BAR; CLUSTER(bR1,afrP,4); BAR;                                             /* ph6 */ \
    if (STEADY) { STAGE((KB)+3,0,0,1); VM2; } \
    BAR; if (STEADY) RD_A2TO(0,0,afrP); CLUSTER(bR1,afrN,6); BAR;                                 /* ph7 */ \
}while(0)

    v4i acc[8][4];
    #pragma unroll
    for (int m = 0; m < 8; ++m)
        #pragma unroll
        for (int n = 0; n < 4; ++n) acc[m][n] = (v4i){0, 0, 0, 0};
    v4i afrP[2][2], afrN[2][2], bR0[4][2], bR1[4][2];

    // prologue: buf0 <- kt0 (B0,B1,A0,A1); buf1.A0 <- kt1; VM2 leaves only b1A0 in flight.
    STAGE(0,1,0,0); STAGE(0,1,1,0); STAGE(0,0,0,0); STAGE(0,0,1,0);
    STAGE(1,0,0,1);
    VM2; BAR;
    RD_B8(0,bR0); RD_A2TO(0,0,afrP);

    for (int i = 0; i < 15; ++i) { ITER(2 * i, 1); }
    ITER(30, 0);

#undef ITER
#undef CLUSTER
#undef RD_B8
#undef RD_A2TO
#undef VM0
#undef VM2
#undef VM4
#undef BAR
#undef STAGE
#undef BRD
#undef ARD

    // ---- epilogue (verified 16x16 C/D mapping) ----
    const float p0  = ((const float*)bias)[0];
    const float ap0 = fabsf(p0);
    const bool bias_is_f32 = (ap0 >= 1e-6f && ap0 <= 1.0f);

    float swv[4], bvv[4];
    #pragma unroll
    for (int n = 0; n < 4; ++n) {
        int col = bx * 256 + wc * 64 + n * 16 + r;
        swv[n] = scale_w[col];
        bvv[n] = bias_is_f32 ? ((const float*)bias)[col]
                             : __half2float(((const __half*)bias)[col]);
    }

    #pragma unroll
    for (int m = 0; m < 8; ++m) {
        float sxr[4];
        #pragma unroll
        for (int q = 0; q < 4; ++q)
            sxr[q] = scale_x[by * 256 + wr * 128 + m * 16 + g * 4 + q] * DIVFACTOR;
        #pragma unroll
        for (int q = 0; q < 4; ++q) {
            int row = by * 256 + wr * 128 + m * 16 + g * 4 + q;
            #pragma unroll
            for (int n = 0; n < 4; ++n) {
                int col = bx * 256 + wc * 64 + n * 16 + r;
                float v = (float)acc[m][n][q] * sxr[q] * swv[n] + bvv[n];
                out[(size_t)row * 4096 + col] = __half2float(__float2half(v));
            }
        }
    }
}

// ---------------- fallback (round-1 fused kernel, used only if ws too small) ----------------
__global__ __launch_bounds__(256) void i8gemm_kernel(
    const int* __restrict__ x, const int* __restrict__ w,
    const float* __restrict__ scale_x, const float* __restrict__ scale_w,
    const void* __restrict__ bias, float* __restrict__ out)
{
    __shared__ int lds[4096];
    const int t = threadIdx.x, bx = blockIdx.x, by = blockIdx.y;
    const int lane = t & 63, wid = t >> 6, wr = wid >> 1, wc = wid & 1;
    const int th = t >> 4, tl = t & 15;
    const int* aptr = x + (size_t)(by * 128 + th) * 4096 + tl * 4;
    const int* bptr = w + (size_t)(bx * 128 + th) * 4096 + tl * 4;
    const int wbase = th * 16 + (tl ^ (((th >> 1) & 3) << 2));
    const int r = lane & 15, g = lane >> 4;
    const int sw4 = (r >> 1) & 3;
    const int a_rd = (wr * 64 + r) * 16 + ((g ^ sw4) << 2);
    const int b_rd = 2048 + (wc * 64 + r) * 16 + ((g ^ sw4) << 2);

    v4i acc[4][4];
    #pragma unroll
    for (int m = 0; m < 4; ++m)
        #pragma unroll
        for (int n = 0; n < 4; ++n) acc[m][n] = (v4i){0, 0, 0, 0};

    int4 va[8], vb[8];
    #pragma unroll
    for (int j = 0; j < 8; ++j) { va[j] = *(const int4*)(aptr + j * 65536); vb[j] = *(const int4*)(bptr + j * 65536); }

    for (int kt = 0; kt < 64; ++kt) {
        __syncthreads();
        #pragma unroll
        for (int j = 0; j < 8; ++j) {
            lds[wbase + j * 256]        = (int)pack4(va[j]);
            lds[2048 + wbase + j * 256] = (int)pack4(vb[j]);
        }
        __syncthreads();
        if (kt < 63) {
            const int* ap = aptr + (kt + 1) * 64;
            const int* bp = bptr + (kt + 1) * 64;
            #pragma unroll
            for (int j = 0; j < 8; ++j) { va[j] = *(const int4*)(ap + j * 65536); vb[j] = *(const int4*)(bp + j * 65536); }
        }
        v4i af[4], bf[4];
        #pragma unroll
        for (int m = 0; m < 4; ++m) af[m] = *(const v4i*)&lds[a_rd + m * 256];
        #pragma unroll
        for (int n = 0; n < 4; ++n) bf[n] = *(const v4i*)&lds[b_rd + n * 256];
        #pragma unroll
        for (int m = 0; m < 4; ++m)
            #pragma unroll
            for (int n = 0; n < 4; ++n)
                acc[m][n] = __builtin_amdgcn_mfma_i32_16x16x64_i8(af[m], bf[n], acc[m][n], 0, 0, 0);
    }

    const float p0 = ((const float*)bias)[0];
    const float ap0 = fabsf(p0);
    const bool bias_is_f32 = (ap0 >= 1e-6f && ap0 <= 1.0f);
    float sxv[4][4];
    #pragma unroll
    for (int m = 0; m < 4; ++m)
        #pragma unroll
        for (int q = 0; q < 4; ++q)
            sxv[m][q] = scale_x[by * 128 + wr * 64 + m * 16 + g * 4 + q] * DIVFACTOR;
    float swv[4], bvv[4];
    #pragma unroll
    for (int n = 0; n < 4; ++n) {
        int col = bx * 128 + wc * 64 + n * 16 + r;
        swv[n] = scale_w[col];
        bvv[n] = bias_is_f32 ? ((const float*)bias)[col] : __half2float(((const __half*)bias)[col]);
    }
    #pragma unroll
    for (int m = 0; m < 4; ++m)
        #pragma unroll
        for (int q = 0; q < 4; ++q) {
            int row = by * 128 + wr * 64 + m * 16 + g * 4 + q;
            float s = sxv[m][q];
            #pragma unroll
            for (int n = 0; n < 4; ++n) {
                int col = bx * 128 + wc * 64 + n * 16 + r;
                float v = (float)acc[m][n][q] * s * swv[n] + bvv[n];
                out[(size_t)row * 4096 + col] = __half2float(__float2half(v));
            }
        }
}

extern "C" void kernel_launch(void* const* d_in, const int* in_sizes, int n_in,
                              void* d_out, int out_size, void* d_ws, size_t ws_size,
                              hipStream_t stream) {
    const int*   x   = (const int*)d_in[0];
    const float* sx  = (const float*)d_in[1];
    const int*   w   = (const int*)d_in[2];
    const float* sw  = (const float*)d_in[3];
    const void*  bi  = d_in[4];
    float*       out = (float*)d_out;
    (void)in_sizes; (void)n_in; (void)out_size;

    if (ws_size >= (size_t)33554432) {
        uint4* ws = (uint4*)d_ws;
        hipLaunchKernelGGL(pack_kernel, dim3(2048, 2, 1), dim3(256, 1, 1), 0, stream, x, w, ws);
        hipLaunchKernelGGL(i8gemm_8ph, dim3(256, 1, 1), dim3(512, 1, 1), 0, stream,
                           ws, ws + 1048576, sx, sw, bi, out);
    } else {
        hipLaunchKernelGGL(i8gemm_kernel, dim3(32, 32, 1), dim3(256, 1, 1), 0, stream,
                           x, w, sx, sw, bi, out);
    }
}